// Round 4
// baseline (1241.393 us; speedup 1.0000x reference)
//
#include <hip/hip_runtime.h>

#define NODES   64
#define FRAMES  4096
#define INCH    9
#define H1DIM   256
#define H2DIM   512
#define NEDGE   256

#define CHUNK   64
#define H1CP    66    // row stride (floats): even (8B-aligned b64 reads), non-pow2
#define ELLW    16    // ELL width; rows with nnz>16 overflow to tail list (P ~ 1e-4)
#define TAILMAX 64

// ---------------------------------------------------------------------------
// prep: dense normalized A (row=dst, self-loops) -> ELL[64][16] of (val,col)
// packed as float2, + overflow tail list. Zero global accumulator.
// Handles int32 or int64 edge_index.
// ---------------------------------------------------------------------------
__global__ void prep_kernel(const int* __restrict__ ei,
                            float* __restrict__ acc,
                            float2* __restrict__ ellG,      // [64][16]
                            int* __restrict__ tailCntG,
                            int* __restrict__ tailRowG,
                            int* __restrict__ tailColG,
                            float* __restrict__ tailValG)
{
    __shared__ float sA[NODES * NODES];
    __shared__ float dis[NODES];
    __shared__ int   deg[NODES];
    __shared__ int   sTail;
    __shared__ int   flag;
    const int t = threadIdx.x;  // 256 threads
    if (t == 0) { flag = 0; sTail = 0; }
    for (int i = t; i < NODES * NODES; i += 256) sA[i] = 0.f;
    if (t < NODES) deg[t] = 1;  // self-loop
    __syncthreads();
    // int64 little-endian => odd dwords are high words of values <64 => all 0.
    if (ei[2 * t + 1] != 0) atomicOr(&flag, 1);
    __syncthreads();
    const bool is64 = (flag == 0);
    int s = 0, d = 0;
    if (t < NEDGE) {
        if (is64) { s = ei[2 * t];   d = ei[512 + 2 * t]; }
        else      { s = ei[t];       d = ei[NEDGE + t];   }
        atomicAdd(&deg[d], 1);
    }
    __syncthreads();
    if (t < NODES) dis[t] = rsqrtf((float)deg[t]);
    __syncthreads();
    if (t < NEDGE) atomicAdd(&sA[d * NODES + s], dis[s] * dis[d]);  // row = dst
    __syncthreads();
    if (t < NODES) sA[t * NODES + t] += dis[t] * dis[t];
    __syncthreads();
    if (t < NODES) {
        int j = 0;
        for (int m = 0; m < NODES; ++m) {
            float v = sA[t * NODES + m];
            if (v != 0.f) {
                if (j < ELLW) {
                    ellG[t * ELLW + j] = make_float2(v, __int_as_float(m));
                } else {
                    int idx = atomicAdd(&sTail, 1);
                    if (idx < TAILMAX) {
                        tailRowG[idx] = t; tailColG[idx] = m; tailValG[idx] = v;
                    }
                }
                ++j;
            }
        }
        for (; j < ELLW; ++j)
            ellG[t * ELLW + j] = make_float2(0.f, __int_as_float(0));
    }
    __syncthreads();
    if (t == 0) *tailCntG = (sTail < TAILMAX) ? sTail : TAILMAX;
    for (int i = t; i < H2DIM; i += 256) acc[i] = 0.f;
}

// ---------------------------------------------------------------------------
// One block per frame. K-chunked (4 x 64) fused GCN.
// GEMM wave tiling: 2 row-groups x 4 col-groups; per lane R=32 rows, C=2 cols
//   -> W2 read 2x per block (1 MB/frame) instead of 8x: L1 demand 64->16 B/cy.
// Aggregation: ELL[16], fully unrolled, independent chains.
// LDS ~51.5 KB -> 2 blocks/CU; launch_bounds(512,2) -> 128 VGPR cap.
// ---------------------------------------------------------------------------
__global__ __launch_bounds__(512, 2)
void frame_kernel(const float* __restrict__ x,
                  const float2* __restrict__ ellG,
                  const int* __restrict__ tailCntG,
                  const int* __restrict__ tailRowG,
                  const int* __restrict__ tailColG,
                  const float* __restrict__ tailValG,
                  const float* __restrict__ W1,
                  const float* __restrict__ b1,
                  const float* __restrict__ W2,
                  const float* __restrict__ b2,
                  float* __restrict__ acc)
{
    __shared__ __align__(16) float2 sEll[NODES][ELLW];   //  8192 B
    __shared__ float sX [NODES][12];                     //  3072 B
    __shared__ float sAX[NODES][12];                     //  3072 B
    __shared__ __align__(16) float sH1c [NODES][H1CP];   // 16896 B
    __shared__ __align__(16) float sAH1c[NODES][H1CP];   // 16896 B
    __shared__ float sPart[H2DIM];                       //  2048 B
    __shared__ int   sTR[TAILMAX];
    __shared__ int   sTC[TAILMAX];
    __shared__ float sTV[TAILMAX];
    __shared__ int   sTCnt;                              // + ~0.8 KB => ~51.5 KB

    const int t  = threadIdx.x;
    const int f  = blockIdx.x;
    const int wv = t >> 6;            // wave 0..7
    const int ln = t & 63;
    const int n0L = wv * 8;           // layer1/agg: rows 8wv..8wv+7, col = ln
    const int rg  = wv >> 2;          // GEMM row group (0..1): rows 32rg..32rg+31
    const int cg  = wv & 3;           // GEMM col group (0..3)
    const int j0  = cg * 128 + ln * 2;// GEMM cols j0, j0+1

    // ---- stage ELL, tail, X ----
    for (int i = t; i < NODES * ELLW; i += 512)
        sEll[i >> 4][i & (ELLW - 1)] = ellG[i];
    if (t == 0) sTCnt = *tailCntG;
    if (t < TAILMAX) { sTR[t] = tailRowG[t]; sTC[t] = tailColG[t]; sTV[t] = tailValG[t]; }
    sPart[t] = 0.f;
    for (int i = t; i < NODES * INCH; i += 512) {
        int n = i / INCH, c = i - n * INCH;
        sX[n][c] = x[(n * FRAMES + f) * INCH + c];
    }
    __syncthreads();

    // ---- AX = A*X via ELL ----
    for (int i = t; i < NODES * INCH; i += 512) {
        int n = i / INCH, c = i - n * INCH;
        float v = 0.f;
        #pragma unroll
        for (int j = 0; j < ELLW; ++j) {
            float2 e = sEll[n][j];
            v = fmaf(e.x, sX[__float_as_int(e.y)][c], v);
        }
        sAX[n][c] = v;
    }
    if (sTCnt > 0) {
        __syncthreads();
        if (t < sTCnt * INCH) {
            int e = t / INCH, c = t - e * INCH;
            atomicAdd(&sAX[sTR[e]][c], sTV[e] * sX[sTC[e]][c]);
        }
    }
    __syncthreads();

    float a2[32][2];
    #pragma unroll
    for (int r = 0; r < 32; ++r) { a2[r][0] = 0.f; a2[r][1] = 0.f; }

    for (int ch = 0; ch < 4; ++ch) {
        const int jb = ch * CHUNK;

        // ---- layer1 chunk: H1c[n][ln] = relu(sum_c AX[n][c]*W1[c][jb+ln]+b1) ----
        {
            float h[8];
            const float bb = b1[jb + ln];
            #pragma unroll
            for (int r = 0; r < 8; ++r) h[r] = bb;
            #pragma unroll
            for (int c = 0; c < INCH; ++c) {
                const float w = W1[c * H1DIM + jb + ln];
                #pragma unroll
                for (int r = 0; r < 8; ++r)
                    h[r] = fmaf(sAX[n0L + r][c], w, h[r]);
            }
            #pragma unroll
            for (int r = 0; r < 8; ++r)
                sH1c[n0L + r][ln] = fmaxf(h[r], 0.f);
        }
        __syncthreads();

        // ---- aggregation: AH1c[n][ln] = sum_j ell(n,j).v * H1c[ell(n,j).c][ln] ----
        #pragma unroll
        for (int r = 0; r < 8; ++r) {
            const int n = n0L + r;
            float v = 0.f;
            #pragma unroll
            for (int j = 0; j < ELLW; ++j) {
                float2 e = sEll[n][j];                       // b64 broadcast
                v = fmaf(e.x, sH1c[__float_as_int(e.y)][ln], v);  // lane-stride-1
            }
            sAH1c[n][ln] = v;
        }
        if (sTCnt > 0) {
            #pragma unroll 1
            for (int e = 0; e < sTCnt; ++e)
                if ((sTR[e] >> 3) == wv)
                    sAH1c[sTR[e]][ln] += sTV[e] * sH1c[sTC[e]][ln];
        }
        __syncthreads();

        // ---- GEMM chunk: a2[r][c] += AH1c[32rg+r][k] * W2[jb+k][j0+c] ----
        const float* w2p = &W2[jb * H2DIM + j0];
        const int n0G = rg * 32;
        for (int k0 = 0; k0 < CHUNK; k0 += 2) {
            const float2 w20 = *(const float2*)(w2p);            // coalesced 512B/wave
            const float2 w21 = *(const float2*)(w2p + H2DIM);
            w2p += 2 * H2DIM;
            #pragma unroll
            for (int rb = 0; rb < 4; ++rb) {
                float2 av[8];
                #pragma unroll
                for (int i = 0; i < 8; ++i)
                    av[i] = *(const float2*)&sAH1c[n0G + rb * 8 + i][k0];  // b64 bcast
                #pragma unroll
                for (int i = 0; i < 8; ++i) {
                    const int r = rb * 8 + i;
                    a2[r][0] = fmaf(av[i].x, w20.x, a2[r][0]);
                    a2[r][1] = fmaf(av[i].x, w20.y, a2[r][1]);
                    a2[r][0] = fmaf(av[i].y, w21.x, a2[r][0]);
                    a2[r][1] = fmaf(av[i].y, w21.y, a2[r][1]);
                }
            }
        }
        __syncthreads();   // protect sH1c/sAH1c for next chunk
    }

    // ---- epilogue: relu + row-sum -> block partial -> global ----
    {
        const float b20 = b2[j0], b21 = b2[j0 + 1];
        float s0 = 0.f, s1 = 0.f;
        #pragma unroll
        for (int r = 0; r < 32; ++r) {
            s0 += fmaxf(a2[r][0] + b20, 0.f);
            s1 += fmaxf(a2[r][1] + b21, 0.f);
        }
        atomicAdd(&sPart[j0],     s0);
        atomicAdd(&sPart[j0 + 1], s1);
    }
    __syncthreads();
    atomicAdd(&acc[t], sPart[t]);
}

// ---------------------------------------------------------------------------
// head: out[c] = (acc/262144) . Wfc[:,c] + bfc[c]
// ---------------------------------------------------------------------------
__global__ void head_kernel(const float* __restrict__ acc,
                            const float* __restrict__ Wfc,
                            const float* __restrict__ bfc,
                            float* __restrict__ out)
{
    const int c = blockIdx.x * 256 + threadIdx.x;
    if (c >= H2DIM) return;
    const float scale = 1.0f / (64.0f * 4096.0f);
    float v = bfc[c];
    for (int j = 0; j < H2DIM; ++j)
        v = fmaf(acc[j] * scale, Wfc[j * H2DIM + c], v);
    out[c] = v;
}

extern "C" void kernel_launch(void* const* d_in, const int* in_sizes, int n_in,
                              void* d_out, int out_size, void* d_ws, size_t ws_size,
                              hipStream_t stream)
{
    const float* x   = (const float*)d_in[0];
    const int*   ei  = (const int*)  d_in[1];
    const float* W1  = (const float*)d_in[2];
    const float* b1  = (const float*)d_in[3];
    const float* W2  = (const float*)d_in[4];
    const float* b2  = (const float*)d_in[5];
    const float* Wfc = (const float*)d_in[6];
    const float* bfc = (const float*)d_in[7];
    float* out = (float*)d_out;

    float*  acc     = (float*)d_ws;                  // 512 f32
    float2* ell     = (float2*)(acc + H2DIM);        // 1024 float2
    int*    tailCnt = (int*)(ell + NODES * ELLW);    // 1
    int*    tailRow = tailCnt + 1;                   // 64
    int*    tailCol = tailRow + TAILMAX;             // 64
    float*  tailVal = (float*)(tailCol + TAILMAX);   // 64

    prep_kernel <<<1,      256, 0, stream>>>(ei, acc, ell, tailCnt,
                                             tailRow, tailCol, tailVal);
    frame_kernel<<<FRAMES, 512, 0, stream>>>(x, ell, tailCnt,
                                             tailRow, tailCol, tailVal,
                                             W1, b1, W2, b2, acc);
    head_kernel <<<2,      256, 0, stream>>>(acc, Wfc, bfc, out);
}